// Round 13
// baseline (71.153 us; speedup 1.0000x reference)
//
#include <hip/hip_runtime.h>

#define NN 50000
#define TT 12
#define QQ 3
#define HH 64
#define KK 32
#define TQ 36    // T*Q
#define RB 64    // encoded row bytes: dwords 0..8 = 36 int8, dword 9 = fp32 scale
#define NPW 7    // nodes per wave: 7 nodes x 9 lanes = 63, lane 63 idle
#define NWAVES ((NN + NPW - 1) / NPW)           // 7143
#define LBLOCKS ((NWAVES + 3) / 4)              // 4 waves per 256-block

// ---------------------------------------------------------------------------
// R13 theory: levels are bound by random 64B-sector touch rate (R12 null:
// halving instrs+waves changed nothing; R11: sector cut -> win). Encode state
// rows into exactly ONE 64B sector: 36 int8 + fp32 row-scale, 64B-aligned.
// ---------------------------------------------------------------------------

__device__ __forceinline__ unsigned int pack4(float v0, float v1, float v2,
                                              float v3, float inv) {
    int q0 = (int)rintf(v0 * inv), q1 = (int)rintf(v1 * inv);
    int q2 = (int)rintf(v2 * inv), q3 = (int)rintf(v3 * inv);
    q0 = q0 > 127 ? 127 : (q0 < -127 ? -127 : q0);
    q1 = q1 > 127 ? 127 : (q1 < -127 ? -127 : q1);
    q2 = q2 > 127 ? 127 : (q2 < -127 ? -127 : q2);
    q3 = q3 > 127 ? 127 : (q3 < -127 ? -127 : q3);
    return (unsigned int)(q0 & 255) | ((unsigned int)(q1 & 255) << 8) |
           ((unsigned int)(q2 & 255) << 16) | ((unsigned int)(q3 & 255) << 24);
}
__device__ __forceinline__ float dec(unsigned int u, int j) {
    return (float)(int)(signed char)(u >> (8 * j));
}

// ---------------------------------------------------------------------------
// Projection in XW-space, fp32 out (aligned dword stores; the level state is
// re-encoded to int8 by encode_kernel). XW = (gnn@w + b) * scaler.
// ---------------------------------------------------------------------------
__global__ __launch_bounds__(256) void proj_xw_kernel(
    const float* __restrict__ gnn, const float* __restrict__ w,
    const float* __restrict__ b, const float* __restrict__ scaler,
    float* __restrict__ xw, int nrows)
{
    const int lane = threadIdx.x & 63;
    const int sub  = lane & 15;
    const int h0   = sub * 4;

    float wreg[4][3];
#pragma unroll
    for (int j = 0; j < 4; ++j)
#pragma unroll
        for (int q = 0; q < 3; ++q)
            wreg[j][q] = w[(h0 + j) * 3 + q];
    const float b0 = b[0], b1 = b[1], b2 = b[2];

    const int gwave  = (blockIdx.x * blockDim.x + threadIdx.x) >> 6;
    const int nwaves = (gridDim.x * blockDim.x) >> 6;
    const int nquads = nrows >> 2;

    for (int quad = gwave; quad < nquads; quad += nwaves) {
        const float4 g = *reinterpret_cast<const float4*>(gnn + (size_t)quad * 256 + lane * 4);
        float a0 = g.x * wreg[0][0] + g.y * wreg[1][0] + g.z * wreg[2][0] + g.w * wreg[3][0];
        float a1 = g.x * wreg[0][1] + g.y * wreg[1][1] + g.z * wreg[2][1] + g.w * wreg[3][1];
        float a2 = g.x * wreg[0][2] + g.y * wreg[1][2] + g.z * wreg[2][2] + g.w * wreg[3][2];
#pragma unroll
        for (int off = 8; off > 0; off >>= 1) {
            a0 += __shfl_down(a0, off);
            a1 += __shfl_down(a1, off);
            a2 += __shfl_down(a2, off);
        }
        if (sub == 0) {
            const int row = quad * 4 + (lane >> 4);   // row = node*T + t
            const float s = scaler[row];
            xw[row * 3 + 0] = (a0 + b0) * s;
            xw[row * 3 + 1] = (a1 + b1) * s;
            xw[row * 3 + 2] = (a2 + b2) * s;
        }
    }
}

// ---------------------------------------------------------------------------
// Encode: thread = node. Read 36 fp32 (9x float4, 144B-aligned rows), compute
// row max, quantize to int8 with scale = max/127, store one 64B row.
// ---------------------------------------------------------------------------
__global__ __launch_bounds__(256) void encode_kernel(
    const float* __restrict__ xw, unsigned char* __restrict__ E)
{
    const int node = blockIdx.x * blockDim.x + threadIdx.x;
    if (node >= NN) return;
    const float4* r4 = reinterpret_cast<const float4*>(xw + (size_t)node * TQ);
    float4 v[9];
#pragma unroll
    for (int j = 0; j < 9; ++j) v[j] = r4[j];
    float mm = 0.0f;
#pragma unroll
    for (int j = 0; j < 9; ++j) {
        mm = fmaxf(mm, fmaxf(fmaxf(fabsf(v[j].x), fabsf(v[j].y)),
                             fmaxf(fabsf(v[j].z), fabsf(v[j].w))));
    }
    const float s   = mm * (1.0f / 127.0f);
    const float inv = mm > 0.0f ? 127.0f / mm : 0.0f;
    unsigned int d[9];
#pragma unroll
    for (int j = 0; j < 9; ++j)
        d[j] = pack4(v[j].x, v[j].y, v[j].z, v[j].w, inv);

    uint4* o = reinterpret_cast<uint4*>(E + (size_t)node * RB);
    o[0] = make_uint4(d[0], d[1], d[2], d[3]);
    o[1] = make_uint4(d[4], d[5], d[6], d[7]);
    o[2] = make_uint4(d[8], __float_as_uint(s), 0u, 0u);
}

// ---------------------------------------------------------------------------
// One level, ping-pong over encoded state. Wave = 7 nodes x 9 lanes.
// Lane (node, p<9): gathers payload dword p + scale dword of each key row
// (same 64B sector!), all 64 loads in flight, fp32 accumulate, then 9-lane
// shuffle max -> requantize own row.
// ---------------------------------------------------------------------------
__global__ __launch_bounds__(256) void level_kernel(
    const unsigned char* __restrict__ Ein, const int* __restrict__ keybom,
    const int* __restrict__ lvl, unsigned char* __restrict__ Eout, int level)
{
    const int gwave = (blockIdx.x * blockDim.x + threadIdx.x) >> 6;
    const int l     = threadIdx.x & 63;
    const int nl    = l / 9;                  // node within wave
    const int p     = l - nl * 9;             // payload dword index
    const int node  = gwave * NPW + nl;
    if (l >= 63 || node >= NN) return;

    const unsigned int* rin  = reinterpret_cast<const unsigned int*>(Ein + (size_t)node * RB);
    unsigned int*       rout = reinterpret_cast<unsigned int*>(Eout + (size_t)node * RB);

    if (lvl[node] != level) {                 // pass-through: 8 lanes copy 64B
        if (p < 8)
            reinterpret_cast<uint2*>(rout)[p] =
                reinterpret_cast<const uint2*>(rin)[p];
        return;
    }

    const int4* kb4 = reinterpret_cast<const int4*>(keybom + (size_t)node * KK);
    int keys[KK];
#pragma unroll
    for (int kk = 0; kk < KK / 4; ++kk) {
        const int4 k4 = kb4[kk];
        keys[kk * 4 + 0] = k4.x; keys[kk * 4 + 1] = k4.y;
        keys[kk * 4 + 2] = k4.z; keys[kk * 4 + 3] = k4.w;
    }
    unsigned int pay[KK]; unsigned int scu[KK];
#pragma unroll
    for (int k = 0; k < KK; ++k) {
        const int key = keys[k];
        const unsigned int* kr = reinterpret_cast<const unsigned int*>(Ein + (size_t)key * RB);
        pay[k] = (key >= 0) ? kr[p] : 0u;     // all loads issued before use
        scu[k] = (key >= 0) ? kr[9] : 0u;
    }
    float a0 = 0.f, a1 = 0.f, a2 = 0.f, a3 = 0.f;
#pragma unroll
    for (int k = 0; k < KK; ++k) {
        const float s = __uint_as_float(scu[k]);
        const unsigned int u = pay[k];
        a0 += dec(u, 0) * s;
        a1 += dec(u, 1) * s;
        a2 += dec(u, 2) * s;
        a3 += dec(u, 3) * s;
    }
    // 9-lane row max (lanes of a node are contiguous within the wave)
    float m = fmaxf(fmaxf(fabsf(a0), fabsf(a1)), fmaxf(fabsf(a2), fabsf(a3)));
    const int base = nl * 9 + (l - p - nl * 9) + 0;  // = nl*9 within wave
    const int wbase = (l / 9) * 9;
    float mm = m;
#pragma unroll
    for (int i = 0; i < 9; ++i) mm = fmaxf(mm, __shfl(m, wbase + i));

    const float s   = mm * (1.0f / 127.0f);
    const float inv = mm > 0.0f ? 127.0f / mm : 0.0f;
    rout[p] = pack4(a0, a1, a2, a3, inv);
    if (p == 0) rout[9] = __float_as_uint(s);
    (void)base;
}

// ---------------------------------------------------------------------------
// Final level fused with decode + divide-by-scaler, fp32 float4 stores.
// ---------------------------------------------------------------------------
__global__ __launch_bounds__(256) void level_final_kernel(
    const unsigned char* __restrict__ Ein, const float* __restrict__ scaler,
    const int* __restrict__ keybom, const int* __restrict__ lvl,
    float* __restrict__ out, int level)
{
    const int gwave = (blockIdx.x * blockDim.x + threadIdx.x) >> 6;
    const int l     = threadIdx.x & 63;
    const int nl    = l / 9;
    const int p     = l - nl * 9;
    const int node  = gwave * NPW + nl;
    if (l >= 63 || node >= NN) return;

    const unsigned int* rin = reinterpret_cast<const unsigned int*>(Ein + (size_t)node * RB);
    float v0, v1, v2, v3;

    if (lvl[node] != level) {
        const unsigned int u = rin[p];
        const float s = __uint_as_float(rin[9]);
        v0 = dec(u, 0) * s; v1 = dec(u, 1) * s;
        v2 = dec(u, 2) * s; v3 = dec(u, 3) * s;
    } else {
        const int4* kb4 = reinterpret_cast<const int4*>(keybom + (size_t)node * KK);
        int keys[KK];
#pragma unroll
        for (int kk = 0; kk < KK / 4; ++kk) {
            const int4 k4 = kb4[kk];
            keys[kk * 4 + 0] = k4.x; keys[kk * 4 + 1] = k4.y;
            keys[kk * 4 + 2] = k4.z; keys[kk * 4 + 3] = k4.w;
        }
        unsigned int pay[KK]; unsigned int scu[KK];
#pragma unroll
        for (int k = 0; k < KK; ++k) {
            const int key = keys[k];
            const unsigned int* kr = reinterpret_cast<const unsigned int*>(Ein + (size_t)key * RB);
            pay[k] = (key >= 0) ? kr[p] : 0u;
            scu[k] = (key >= 0) ? kr[9] : 0u;
        }
        v0 = v1 = v2 = v3 = 0.f;
#pragma unroll
        for (int k = 0; k < KK; ++k) {
            const float s = __uint_as_float(scu[k]);
            const unsigned int u = pay[k];
            v0 += dec(u, 0) * s;
            v1 += dec(u, 1) * s;
            v2 += dec(u, 2) * s;
            v3 += dec(u, 3) * s;
        }
    }
    const int e0 = node * TQ + 4 * p;
    const float4 r = make_float4(v0 / scaler[(e0 + 0) / 3],
                                 v1 / scaler[(e0 + 1) / 3],
                                 v2 / scaler[(e0 + 2) / 3],
                                 v3 / scaler[(e0 + 3) / 3]);
    *reinterpret_cast<float4*>(out + e0) = r;   // 144n + 16p: 16B-aligned
}

extern "C" void kernel_launch(void* const* d_in, const int* in_sizes, int n_in,
                              void* d_out, int out_size, void* d_ws, size_t ws_size,
                              hipStream_t stream)
{
    const float* gnn    = (const float*)d_in[0];
    const float* w      = (const float*)d_in[1];
    const float* b      = (const float*)d_in[2];
    const float* scaler = (const float*)d_in[3];
    const int*   keybom = (const int*)d_in[4];
    const int*   lvl    = (const int*)d_in[5];
    float* out = (float*)d_out;

    char* ws = (char*)d_ws;
    float*         XW = (float*)ws;                              // 7.2 MB fp32
    unsigned char* E0 = (unsigned char*)(ws + (size_t)NN * TQ * 4);      // 3.2 MB
    unsigned char* E1 = E0 + (size_t)NN * RB;                            // 3.2 MB

    proj_xw_kernel<<<2048, 256, 0, stream>>>(gnn, w, b, scaler, XW, NN * TT);
    encode_kernel<<<(NN + 255) / 256, 256, 0, stream>>>(XW, E0);

    level_kernel<<<LBLOCKS, 256, 0, stream>>>(E0, keybom, lvl, E1, 1);
    level_kernel<<<LBLOCKS, 256, 0, stream>>>(E1, keybom, lvl, E0, 2);
    level_final_kernel<<<LBLOCKS, 256, 0, stream>>>(E0, scaler, keybom, lvl, out, 3);
}